// Round 1
// baseline (419.012 us; speedup 1.0000x reference)
//
#include <hip/hip_runtime.h>

// OneToOneLinear: out = sigmoid(SCALE * (input * weight + bias)),
// weight/bias broadcast per-feature. N=32768 rows x FEATURES=2048, fp32.
// Memory-bound elementwise: ~537 MB total traffic -> ~85us floor @ 6.3 TB/s.

#define FEATURES 2048
#define SCALE_F  4.0f

__global__ __launch_bounds__(256) void
OneToOneLinear_24807731102291_kernel(const float4* __restrict__ in,
                                     const float4* __restrict__ w,
                                     const float4* __restrict__ b,
                                     float4* __restrict__ out,
                                     int nvec) {
    int i = blockIdx.x * blockDim.x + threadIdx.x;
    if (i >= nvec) return;

    // feature vector index: 4 consecutive features per float4; FEATURES/4=512 (pow2)
    int fv = i & (FEATURES / 4 - 1);

    float4 x  = in[i];
    float4 wv = w[fv];   // 8 KB array -> L1/L2 resident, no HBM cost
    float4 bv = b[fv];

    float4 r;
    r.x = 1.0f / (1.0f + __expf(-SCALE_F * (x.x * wv.x + bv.x)));
    r.y = 1.0f / (1.0f + __expf(-SCALE_F * (x.y * wv.y + bv.y)));
    r.z = 1.0f / (1.0f + __expf(-SCALE_F * (x.z * wv.z + bv.z)));
    r.w = 1.0f / (1.0f + __expf(-SCALE_F * (x.w * wv.w + bv.w)));

    out[i] = r;
}

extern "C" void kernel_launch(void* const* d_in, const int* in_sizes, int n_in,
                              void* d_out, int out_size, void* d_ws, size_t ws_size,
                              hipStream_t stream) {
    const float4* in = (const float4*)d_in[0];   // (N, FEATURES) fp32
    const float4* w  = (const float4*)d_in[1];   // (FEATURES,)   fp32
    const float4* b  = (const float4*)d_in[2];   // (FEATURES,)   fp32
    float4* out      = (float4*)d_out;

    int nvec = out_size / 4;                     // 33554432/4 = 16777216
    int block = 256;
    int grid = (nvec + block - 1) / block;       // 65536 blocks

    OneToOneLinear_24807731102291_kernel<<<grid, block, 0, stream>>>(in, w, b, out, nvec);
}